// Round 2
// baseline (884.501 us; speedup 1.0000x reference)
//
#include <hip/hip_runtime.h>
#include <stdint.h>

// Pairwise-HMM forward DP, 1024x1024, S=3.
// 16 column-stripes x 64 lanes (1 wave/stripe), skew-1 anti-diagonal wavefront.
// State: mantissa-normalized linear values w_s = F_s*2^-r with integer exponent r
// (no transcendentals on the dependent chain). e^(A+theta) precomputed into d_ws
// by prep_kernel (fallback: inline __expf if ws too small).
// Cross-stripe boundary: per row, THREE independently self-tagged u64 packets
// (float bits | (r<<12|tag) in high word), relaxed AGENT atomics, verified
// prefetch pipeline 3 rows deep. tag=row+1: 0xAA poison (0xAAA) & zeros never match.

#define NN    1024
#define NSTR  16
#define SW    64
#define NIT   1088          // 1087 steps padded to a multiple of 8
#define E_OFF (512*1024)

__device__ __forceinline__ uint64_t pk_load(const uint64_t* p){
  return __hip_atomic_load(p, __ATOMIC_RELAXED, __HIP_MEMORY_SCOPE_AGENT);
}
__device__ __forceinline__ void pk_store(uint64_t* p, uint64_t v){
  __hip_atomic_store(p, v, __ATOMIC_RELAXED, __HIP_MEMORY_SCOPE_AGENT);
}
__device__ __forceinline__ bool tag_ok(uint64_t pkt, uint32_t tag){
  return ((uint32_t)(pkt >> 32) & 0xFFFu) == tag;
}

__global__ __launch_bounds__(256) void prep_kernel(const float* __restrict__ theta,
                                                   const float* __restrict__ A,
                                                   float* __restrict__ E){
  int cell = blockIdx.x*256 + threadIdx.x;
  if (cell >= NN*NN) return;
  const float* a  = A + (size_t)cell*9;
  const float* th = theta + (size_t)cell*3;
  float t0 = th[0], t1 = th[1], t2 = th[2];
  float4 e0 = make_float4(expf(a[0]+t0), expf(a[1]+t0), expf(a[2]+t0), 0.f);
  float4 e1 = make_float4(expf(a[3]+t1), expf(a[4]+t1), expf(a[5]+t1), 0.f);
  float4 e2 = make_float4(expf(a[6]+t2), expf(a[7]+t2), expf(a[8]+t2), 0.f);
  float4* o = (float4*)(E + (size_t)cell*12);
  o[0]=e0; o[1]=e1; o[2]=e2;
}

template<bool PRE>
__global__ __launch_bounds__(64) void fwd_kernel(const float* __restrict__ theta,
                                                 const float* __restrict__ A,
                                                 const float* __restrict__ Epre,
                                                 uint64_t* __restrict__ pk,
                                                 float* __restrict__ out)
{
  const int c = (int)threadIdx.x;          // lane = column within stripe
  const int s = (int)blockIdx.x;           // stripe
  const int j = s*SW + c;                  // global column (theta/A col index)
  const bool cons = (s > 0)      && (c == 0);
  const bool prod = (s < NSTR-1) && (c == 63);
  const uint64_t* rp = pk + (size_t)(s-1)*NN*3;   // read side (cons only)
  uint64_t*       wp = pk + (size_t)s*NN*3;       // write side (prod only)

  // state: own previous-row output (UP) and diag-hold (last step's left-in)
  float uw0=0.f, uw1=0.f, uw2=0.f; int ur=0;
  float dw0=0.f, dw1=0.f, dw2=0.f; int dr=0;   // real init happens at t==c reset

  uint64_t q0[8], q1[8], q2[8];   // consumer packet ring
  #pragma unroll
  for (int k=0;k<8;++k){ q0[k]=0ull; q1[k]=0ull; q2[k]=0ull; }

  float4 pe0[8], pe1[8], pe2[8];  // PRE: E prefetch ring, 8 rows deep
  float  praw[4][12];             // !PRE: raw A/theta ring, 4 rows deep

  if (PRE){
    #pragma unroll
    for (int k=0;k<8;++k){
      int rr = k - c; rr = rr < 0 ? 0 : rr;
      const float4* ep = (const float4*)(Epre + (size_t)(rr*NN + j)*12);
      pe0[k]=ep[0]; pe1[k]=ep[1]; pe2[k]=ep[2];
    }
  } else {
    #pragma unroll
    for (int k=0;k<4;++k){
      int rr = k - c; rr = rr < 0 ? 0 : rr;
      const float* ap = A + (size_t)(rr*NN + j)*9;
      const float* tp = theta + (size_t)(rr*NN + j)*3;
      #pragma unroll
      for (int q=0;q<9;++q) praw[k][q] = ap[q];
      praw[k][9]=tp[0]; praw[k][10]=tp[1]; praw[k][11]=tp[2];
    }
  }

  // consumer warm-up: rows 0..5 issued; rows 0..2 fully verified
  if (cons){
    #pragma unroll
    for (int k=0;k<6;++k){
      q0[k]=pk_load(rp + k*3+0);
      q1[k]=pk_load(rp + k*3+1);
      q2[k]=pk_load(rp + k*3+2);
    }
    #pragma unroll
    for (int k=0;k<3;++k){
      const uint32_t tag = (uint32_t)(k+1);
      int g;
      g=0; while(!tag_ok(q0[k],tag) && ++g<(1<<16)){ __builtin_amdgcn_s_sleep(8); q0[k]=pk_load(rp+k*3+0); }
      g=0; while(!tag_ok(q1[k],tag) && ++g<(1<<16)){ __builtin_amdgcn_s_sleep(8); q1[k]=pk_load(rp+k*3+1); }
      g=0; while(!tag_ok(q2[k],tag) && ++g<(1<<16)){ __builtin_amdgcn_s_sleep(8); q2[k]=pk_load(rp+k*3+2); }
    }
  }

  for (int tb = 0; tb < NIT; tb += 8){
    #pragma unroll
    for (int u = 0; u < 8; ++u){
      const int t = tb + u;                 // lane c computes theta-row i = t - c

      // left-in from lane c-1's previous-step output
      float l0 = __shfl_up(uw0, 1);
      float l1 = __shfl_up(uw1, 1);
      float l2 = __shfl_up(uw2, 1);
      int   lr = __shfl_up(ur , 1);

      if (c == 0){
        if (s == 0 || t > NN-1){ l0=0.f; l1=0.f; l2=0.f; lr=0; }
        else {
          l0 = __uint_as_float((uint32_t)q0[u]);
          l1 = __uint_as_float((uint32_t)q1[u]);
          l2 = __uint_as_float((uint32_t)q2[u]);
          lr = ((int)(uint32_t)(q2[u] >> 32)) >> 12;
        }
      }

      // first real cell for this lane: kill warm-up garbage state.
      // up-in := V[0][j+1] = NEG_INF -> 0 ; diag-in := V[0][j] = NEG_INF -> 0,
      // except the origin (s==0,c==0): V[0][0] = 0 -> w=(1,1,1), r=0.
      if (tb < SW){                          // uniform guard: t==c implies tb<64
        if (t == c){
          uw0=0.f; uw1=0.f; uw2=0.f; ur=0;
          float dv = (s==0 && c==0) ? 1.0f : 0.0f;
          dw0=dv; dw1=dv; dw2=dv; dr=0;
        }
      }

      float e00,e01,e02,e10,e11,e12,e20,e21,e22;
      if (PRE){
        e00=pe0[u].x; e01=pe0[u].y; e02=pe0[u].z;
        e10=pe1[u].x; e11=pe1[u].y; e12=pe1[u].z;
        e20=pe2[u].x; e21=pe2[u].y; e22=pe2[u].z;
      } else {
        const int sl = u & 3;
        float th0=praw[sl][9], th1=praw[sl][10], th2=praw[sl][11];
        e00=__expf(praw[sl][0]+th0); e01=__expf(praw[sl][1]+th0); e02=__expf(praw[sl][2]+th0);
        e10=__expf(praw[sl][3]+th1); e11=__expf(praw[sl][4]+th1); e12=__expf(praw[sl][5]+th1);
        e20=__expf(praw[sl][6]+th2); e21=__expf(praw[sl][7]+th2); e22=__expf(praw[sl][8]+th2);
      }

      // three dots: k0<-diag, k1<-up, k2<-left; 1e-30 floor keeps dots positive
      float d0 = fmaf(dw2,e02, fmaf(dw1,e01, fmaf(dw0,e00, 1e-30f)));
      float d1 = fmaf(uw2,e12, fmaf(uw1,e11, fmaf(uw0,e10, 1e-30f)));
      float d2 = fmaf(l2 ,e22, fmaf(l1 ,e21, fmaf(l0 ,e20, 1e-30f)));

      // exponent bookkeeping: d = m*2^e with m in [0.5,1)
      int b0 = __float_as_int(d0);
      int b1 = __float_as_int(d1);
      int b2 = __float_as_int(d2);
      int t0 = dr + ((b0 >> 23) & 0xFF) - 126;
      int t1 = ur + ((b1 >> 23) & 0xFF) - 126;
      int t2 = lr + ((b2 >> 23) & 0xFF) - 126;
      int rn = t0 > t1 ? t0 : t1; rn = rn > t2 ? rn : t2;
      float m0 = __int_as_float((b0 & 0x7FFFFF) | 0x3F000000);
      float m1 = __int_as_float((b1 & 0x7FFFFF) | 0x3F000000);
      float m2 = __int_as_float((b2 & 0x7FFFFF) | 0x3F000000);
      float nw0 = ldexpf(m0, t0 - rn);
      float nw1 = ldexpf(m1, t1 - rn);
      float nw2 = ldexpf(m2, t2 - rn);

      if (u == 6){                          // t == 1086 only when tb == NIT-8
        if (tb == NIT-8 && s == NSTR-1 && c == 63){
          out[0] = (log2f(nw0+nw1+nw2) + (float)rn) * 0.6931471805599453f;
        }
      }

      if (prod){
        int i = t - 63;
        if (i >= 0 && i < NN){
          uint64_t meta = ((uint64_t)((uint32_t)(rn << 12) | (uint32_t)(i+1))) << 32;
          pk_store(wp + i*3+0, meta | (uint64_t)__float_as_uint(nw0));
          pk_store(wp + i*3+1, meta | (uint64_t)__float_as_uint(nw1));
          pk_store(wp + i*3+2, meta | (uint64_t)__float_as_uint(nw2));
        }
      }

      if (cons){
        int v = t + 3;                      // verify row v (needed at step v)
        if (v < NN){
          const int sv = (u+3)&7;
          const uint32_t tag = (uint32_t)(v+1);
          if (!tag_ok(q0[sv],tag)){ int g=0; do{ __builtin_amdgcn_s_sleep(2); q0[sv]=pk_load(rp+v*3+0); }while(!tag_ok(q0[sv],tag) && ++g<(1<<16)); }
          if (!tag_ok(q1[sv],tag)){ int g=0; do{ __builtin_amdgcn_s_sleep(2); q1[sv]=pk_load(rp+v*3+1); }while(!tag_ok(q1[sv],tag) && ++g<(1<<16)); }
          if (!tag_ok(q2[sv],tag)){ int g=0; do{ __builtin_amdgcn_s_sleep(2); q2[sv]=pk_load(rp+v*3+2); }while(!tag_ok(q2[sv],tag) && ++g<(1<<16)); }
        }
        int w = t + 6;                      // keep pipeline 3 rows deep
        if (w < NN){
          const int sw_ = (u+6)&7;
          q0[sw_]=pk_load(rp + w*3+0);
          q1[sw_]=pk_load(rp + w*3+1);
          q2[sw_]=pk_load(rp + w*3+2);
        }
      }

      // E/A prefetch for the row used 8 (resp. 4) steps ahead
      if (PRE){
        int rr = t + 8 - c; rr = rr < 0 ? 0 : rr; rr = rr > NN-1 ? NN-1 : rr;
        const float4* ep = (const float4*)(Epre + (size_t)(rr*NN + j)*12);
        pe0[u]=ep[0]; pe1[u]=ep[1]; pe2[u]=ep[2];
      } else {
        int rr = t + 4 - c; rr = rr < 0 ? 0 : rr; rr = rr > NN-1 ? NN-1 : rr;
        const int sl = u & 3;
        const float* ap = A + (size_t)(rr*NN + j)*9;
        const float* tp = theta + (size_t)(rr*NN + j)*3;
        #pragma unroll
        for (int q=0;q<9;++q) praw[sl][q] = ap[q];
        praw[sl][9]=tp[0]; praw[sl][10]=tp[1]; praw[sl][11]=tp[2];
      }

      // rotate: this step's left-in becomes next step's diag; output becomes UP
      dw0=l0; dw1=l1; dw2=l2; dr=lr;
      uw0=nw0; uw1=nw1; uw2=nw2; ur=rn;
    }
  }
}

extern "C" void kernel_launch(void* const* d_in, const int* in_sizes, int n_in,
                              void* d_out, int out_size, void* d_ws, size_t ws_size,
                              hipStream_t stream)
{
  const float* theta = (const float*)d_in[0];
  const float* A     = (const float*)d_in[1];
  float* out = (float*)d_out;
  uint64_t* pk = (uint64_t*)d_ws;                       // 16*1024*3*8 = 393 KiB
  float* E     = (float*)((char*)d_ws + E_OFF);
  size_t need = (size_t)E_OFF + (size_t)NN*NN*48;
  if (ws_size >= need){
    prep_kernel<<<dim3(NN*NN/256), dim3(256), 0, stream>>>(theta, A, E);
    fwd_kernel<true><<<dim3(NSTR), dim3(64), 0, stream>>>(theta, A, E, pk, out);
  } else {
    fwd_kernel<false><<<dim3(NSTR), dim3(64), 0, stream>>>(theta, A, E, pk, out);
  }
}

// Round 8
// 882.369 us; speedup vs baseline: 1.0024x; 1.0024x over previous
//
#include <hip/hip_runtime.h>
#include <stdint.h>

// Pairwise-HMM forward DP, 1024x1024, S=3.
// 16 column-stripes x 64 lanes (1 wave/stripe), skew-1 anti-diagonal wavefront.
// State: mantissa-normalized linear values w_s = F_s*2^-r with integer exponent r
// (no transcendentals on the dependent chain). e^(A+theta) precomputed into d_ws
// by prep_kernel (fallback: inline __expf if ws too small).
// Cross-stripe boundary: per row, THREE independently self-tagged u64 packets
// (float bits | (r<<12|tag) in high word), relaxed AGENT atomics, verified
// prefetch pipeline 3 rows deep. tag=row+1: 0xAA poison (0xAAA) & zeros never match.
//
// R2 change vs R1: __launch_bounds__(64, 1) on fwd_kernel.
// R1 counters showed VGPR_Count=88 (< the ~170 the prefetch rings need) and
// ~1MB of unexplained WRITE_SIZE == scratch spill traffic: the missing 2nd
// launch_bounds arg let the backend target high occupancy and spill the rings,
// costing ~1800 cyc/step. min-1-wave/EU raises the budget to 512 VGPRs.
// (R3-R7 benches never ran — GPU acquisition timeouts — unchanged resubmit.)

#define NN    1024
#define NSTR  16
#define SW    64
#define NIT   1088          // 1087 steps padded to a multiple of 8
#define E_OFF (512*1024)

__device__ __forceinline__ uint64_t pk_load(const uint64_t* p){
  return __hip_atomic_load(p, __ATOMIC_RELAXED, __HIP_MEMORY_SCOPE_AGENT);
}
__device__ __forceinline__ void pk_store(uint64_t* p, uint64_t v){
  __hip_atomic_store(p, v, __ATOMIC_RELAXED, __HIP_MEMORY_SCOPE_AGENT);
}
__device__ __forceinline__ bool tag_ok(uint64_t pkt, uint32_t tag){
  return ((uint32_t)(pkt >> 32) & 0xFFFu) == tag;
}

__global__ __launch_bounds__(256) void prep_kernel(const float* __restrict__ theta,
                                                   const float* __restrict__ A,
                                                   float* __restrict__ E){
  int cell = blockIdx.x*256 + threadIdx.x;
  if (cell >= NN*NN) return;
  const float* a  = A + (size_t)cell*9;
  const float* th = theta + (size_t)cell*3;
  float t0 = th[0], t1 = th[1], t2 = th[2];
  float4 e0 = make_float4(expf(a[0]+t0), expf(a[1]+t0), expf(a[2]+t0), 0.f);
  float4 e1 = make_float4(expf(a[3]+t1), expf(a[4]+t1), expf(a[5]+t1), 0.f);
  float4 e2 = make_float4(expf(a[6]+t2), expf(a[7]+t2), expf(a[8]+t2), 0.f);
  float4* o = (float4*)(E + (size_t)cell*12);
  o[0]=e0; o[1]=e1; o[2]=e2;
}

template<bool PRE>
__global__ __launch_bounds__(64, 1) void fwd_kernel(const float* __restrict__ theta,
                                                 const float* __restrict__ A,
                                                 const float* __restrict__ Epre,
                                                 uint64_t* __restrict__ pk,
                                                 float* __restrict__ out)
{
  const int c = (int)threadIdx.x;          // lane = column within stripe
  const int s = (int)blockIdx.x;           // stripe
  const int j = s*SW + c;                  // global column (theta/A col index)
  const bool cons = (s > 0)      && (c == 0);
  const bool prod = (s < NSTR-1) && (c == 63);
  const uint64_t* rp = pk + (size_t)(s-1)*NN*3;   // read side (cons only)
  uint64_t*       wp = pk + (size_t)s*NN*3;       // write side (prod only)

  // state: own previous-row output (UP) and diag-hold (last step's left-in)
  float uw0=0.f, uw1=0.f, uw2=0.f; int ur=0;
  float dw0=0.f, dw1=0.f, dw2=0.f; int dr=0;   // real init happens at t==c reset

  uint64_t q0[8], q1[8], q2[8];   // consumer packet ring
  #pragma unroll
  for (int k=0;k<8;++k){ q0[k]=0ull; q1[k]=0ull; q2[k]=0ull; }

  float4 pe0[8], pe1[8], pe2[8];  // PRE: E prefetch ring, 8 rows deep
  float  praw[4][12];             // !PRE: raw A/theta ring, 4 rows deep

  if (PRE){
    #pragma unroll
    for (int k=0;k<8;++k){
      int rr = k - c; rr = rr < 0 ? 0 : rr;
      const float4* ep = (const float4*)(Epre + (size_t)(rr*NN + j)*12);
      pe0[k]=ep[0]; pe1[k]=ep[1]; pe2[k]=ep[2];
    }
  } else {
    #pragma unroll
    for (int k=0;k<4;++k){
      int rr = k - c; rr = rr < 0 ? 0 : rr;
      const float* ap = A + (size_t)(rr*NN + j)*9;
      const float* tp = theta + (size_t)(rr*NN + j)*3;
      #pragma unroll
      for (int q=0;q<9;++q) praw[k][q] = ap[q];
      praw[k][9]=tp[0]; praw[k][10]=tp[1]; praw[k][11]=tp[2];
    }
  }

  // consumer warm-up: rows 0..5 issued; rows 0..2 fully verified
  if (cons){
    #pragma unroll
    for (int k=0;k<6;++k){
      q0[k]=pk_load(rp + k*3+0);
      q1[k]=pk_load(rp + k*3+1);
      q2[k]=pk_load(rp + k*3+2);
    }
    #pragma unroll
    for (int k=0;k<3;++k){
      const uint32_t tag = (uint32_t)(k+1);
      int g;
      g=0; while(!tag_ok(q0[k],tag) && ++g<(1<<16)){ __builtin_amdgcn_s_sleep(8); q0[k]=pk_load(rp+k*3+0); }
      g=0; while(!tag_ok(q1[k],tag) && ++g<(1<<16)){ __builtin_amdgcn_s_sleep(8); q1[k]=pk_load(rp+k*3+1); }
      g=0; while(!tag_ok(q2[k],tag) && ++g<(1<<16)){ __builtin_amdgcn_s_sleep(8); q2[k]=pk_load(rp+k*3+2); }
    }
  }

  for (int tb = 0; tb < NIT; tb += 8){
    #pragma unroll
    for (int u = 0; u < 8; ++u){
      const int t = tb + u;                 // lane c computes theta-row i = t - c

      // left-in from lane c-1's previous-step output
      float l0 = __shfl_up(uw0, 1);
      float l1 = __shfl_up(uw1, 1);
      float l2 = __shfl_up(uw2, 1);
      int   lr = __shfl_up(ur , 1);

      if (c == 0){
        if (s == 0 || t > NN-1){ l0=0.f; l1=0.f; l2=0.f; lr=0; }
        else {
          l0 = __uint_as_float((uint32_t)q0[u]);
          l1 = __uint_as_float((uint32_t)q1[u]);
          l2 = __uint_as_float((uint32_t)q2[u]);
          lr = ((int)(uint32_t)(q2[u] >> 32)) >> 12;
        }
      }

      // first real cell for this lane: kill warm-up garbage state.
      // up-in := V[0][j+1] = NEG_INF -> 0 ; diag-in := V[0][j] = NEG_INF -> 0,
      // except the origin (s==0,c==0): V[0][0] = 0 -> w=(1,1,1), r=0.
      if (tb < SW){                          // uniform guard: t==c implies tb<64
        if (t == c){
          uw0=0.f; uw1=0.f; uw2=0.f; ur=0;
          float dv = (s==0 && c==0) ? 1.0f : 0.0f;
          dw0=dv; dw1=dv; dw2=dv; dr=0;
        }
      }

      float e00,e01,e02,e10,e11,e12,e20,e21,e22;
      if (PRE){
        e00=pe0[u].x; e01=pe0[u].y; e02=pe0[u].z;
        e10=pe1[u].x; e11=pe1[u].y; e12=pe1[u].z;
        e20=pe2[u].x; e21=pe2[u].y; e22=pe2[u].z;
      } else {
        const int sl = u & 3;
        float th0=praw[sl][9], th1=praw[sl][10], th2=praw[sl][11];
        e00=__expf(praw[sl][0]+th0); e01=__expf(praw[sl][1]+th0); e02=__expf(praw[sl][2]+th0);
        e10=__expf(praw[sl][3]+th1); e11=__expf(praw[sl][4]+th1); e12=__expf(praw[sl][5]+th1);
        e20=__expf(praw[sl][6]+th2); e21=__expf(praw[sl][7]+th2); e22=__expf(praw[sl][8]+th2);
      }

      // three dots: k0<-diag, k1<-up, k2<-left; 1e-30 floor keeps dots positive
      float d0 = fmaf(dw2,e02, fmaf(dw1,e01, fmaf(dw0,e00, 1e-30f)));
      float d1 = fmaf(uw2,e12, fmaf(uw1,e11, fmaf(uw0,e10, 1e-30f)));
      float d2 = fmaf(l2 ,e22, fmaf(l1 ,e21, fmaf(l0 ,e20, 1e-30f)));

      // exponent bookkeeping: d = m*2^e with m in [0.5,1)
      int b0 = __float_as_int(d0);
      int b1 = __float_as_int(d1);
      int b2 = __float_as_int(d2);
      int t0 = dr + ((b0 >> 23) & 0xFF) - 126;
      int t1 = ur + ((b1 >> 23) & 0xFF) - 126;
      int t2 = lr + ((b2 >> 23) & 0xFF) - 126;
      int rn = t0 > t1 ? t0 : t1; rn = rn > t2 ? rn : t2;
      float m0 = __int_as_float((b0 & 0x7FFFFF) | 0x3F000000);
      float m1 = __int_as_float((b1 & 0x7FFFFF) | 0x3F000000);
      float m2 = __int_as_float((b2 & 0x7FFFFF) | 0x3F000000);
      float nw0 = ldexpf(m0, t0 - rn);
      float nw1 = ldexpf(m1, t1 - rn);
      float nw2 = ldexpf(m2, t2 - rn);

      if (u == 6){                          // t == 1086 only when tb == NIT-8
        if (tb == NIT-8 && s == NSTR-1 && c == 63){
          out[0] = (log2f(nw0+nw1+nw2) + (float)rn) * 0.6931471805599453f;
        }
      }

      if (prod){
        int i = t - 63;
        if (i >= 0 && i < NN){
          uint64_t meta = ((uint64_t)((uint32_t)(rn << 12) | (uint32_t)(i+1))) << 32;
          pk_store(wp + i*3+0, meta | (uint64_t)__float_as_uint(nw0));
          pk_store(wp + i*3+1, meta | (uint64_t)__float_as_uint(nw1));
          pk_store(wp + i*3+2, meta | (uint64_t)__float_as_uint(nw2));
        }
      }

      if (cons){
        int v = t + 3;                      // verify row v (needed at step v)
        if (v < NN){
          const int sv = (u+3)&7;
          const uint32_t tag = (uint32_t)(v+1);
          if (!tag_ok(q0[sv],tag)){ int g=0; do{ __builtin_amdgcn_s_sleep(2); q0[sv]=pk_load(rp+v*3+0); }while(!tag_ok(q0[sv],tag) && ++g<(1<<16)); }
          if (!tag_ok(q1[sv],tag)){ int g=0; do{ __builtin_amdgcn_s_sleep(2); q1[sv]=pk_load(rp+v*3+1); }while(!tag_ok(q1[sv],tag) && ++g<(1<<16)); }
          if (!tag_ok(q2[sv],tag)){ int g=0; do{ __builtin_amdgcn_s_sleep(2); q2[sv]=pk_load(rp+v*3+2); }while(!tag_ok(q2[sv],tag) && ++g<(1<<16)); }
        }
        int w = t + 6;                      // keep pipeline 3 rows deep
        if (w < NN){
          const int sw_ = (u+6)&7;
          q0[sw_]=pk_load(rp + w*3+0);
          q1[sw_]=pk_load(rp + w*3+1);
          q2[sw_]=pk_load(rp + w*3+2);
        }
      }

      // E/A prefetch for the row used 8 (resp. 4) steps ahead
      if (PRE){
        int rr = t + 8 - c; rr = rr < 0 ? 0 : rr; rr = rr > NN-1 ? NN-1 : rr;
        const float4* ep = (const float4*)(Epre + (size_t)(rr*NN + j)*12);
        pe0[u]=ep[0]; pe1[u]=ep[1]; pe2[u]=ep[2];
      } else {
        int rr = t + 4 - c; rr = rr < 0 ? 0 : rr; rr = rr > NN-1 ? NN-1 : rr;
        const int sl = u & 3;
        const float* ap = A + (size_t)(rr*NN + j)*9;
        const float* tp = theta + (size_t)(rr*NN + j)*3;
        #pragma unroll
        for (int q=0;q<9;++q) praw[sl][q] = ap[q];
        praw[sl][9]=tp[0]; praw[sl][10]=tp[1]; praw[sl][11]=tp[2];
      }

      // rotate: this step's left-in becomes next step's diag; output becomes UP
      dw0=l0; dw1=l1; dw2=l2; dr=lr;
      uw0=nw0; uw1=nw1; uw2=nw2; ur=rn;
    }
  }
}

extern "C" void kernel_launch(void* const* d_in, const int* in_sizes, int n_in,
                              void* d_out, int out_size, void* d_ws, size_t ws_size,
                              hipStream_t stream)
{
  const float* theta = (const float*)d_in[0];
  const float* A     = (const float*)d_in[1];
  float* out = (float*)d_out;
  uint64_t* pk = (uint64_t*)d_ws;                       // 16*1024*3*8 = 393 KiB
  float* E     = (float*)((char*)d_ws + E_OFF);
  size_t need = (size_t)E_OFF + (size_t)NN*NN*48;
  if (ws_size >= need){
    prep_kernel<<<dim3(NN*NN/256), dim3(256), 0, stream>>>(theta, A, E);
    fwd_kernel<true><<<dim3(NSTR), dim3(64), 0, stream>>>(theta, A, E, pk, out);
  } else {
    fwd_kernel<false><<<dim3(NSTR), dim3(64), 0, stream>>>(theta, A, E, pk, out);
  }
}